// Round 1
// baseline (4678.849 us; speedup 1.0000x reference)
//
#include <hip/hip_runtime.h>
#include <hip/hip_bf16.h>
#include <math.h>

#define B_   8
#define CIN  32
#define COUT 64
#define KK_  4
#define DD   32
#define HH   64
#define WW   64
#define HW   (HH*WW)        // 4096
#define DHW  (DD*HH*WW)     // 131072

// ---------------- 1) global average pool: p[b][c] ----------------
__global__ void pool_kernel(const float* __restrict__ x, float* __restrict__ p) {
    const int row = blockIdx.x;  // b*CIN + c
    const float4* xr = (const float4*)(x + (size_t)row * DHW);
    float s = 0.f;
    for (int i = threadIdx.x; i < DHW/4; i += 256) {
        float4 v = xr[i];
        s += (v.x + v.y) + (v.z + v.w);
    }
    __shared__ float red[256];
    red[threadIdx.x] = s;
    __syncthreads();
    for (int off = 128; off > 0; off >>= 1) {
        if (threadIdx.x < off) red[threadIdx.x] += red[threadIdx.x + off];
        __syncthreads();
    }
    if (threadIdx.x == 0) p[row] = red[0] * (1.f / (float)DHW);
}

// ---------------- 2) attention MLP + softmax + agg bias ----------------
__device__ __forceinline__ float gelu_erf(float v) {
    return 0.5f * v * (1.f + erff(v * 0.70710678118654752f));
}

__global__ void attn_kernel(const float* __restrict__ p,
                            const float* __restrict__ temperature,
                            const float* __restrict__ bn1_g, const float* __restrict__ bn1_b,
                            const float* __restrict__ w1,    const float* __restrict__ b1,
                            const float* __restrict__ bn2_g, const float* __restrict__ bn2_b,
                            const float* __restrict__ w2,    const float* __restrict__ b2,
                            const float* __restrict__ bn3_g, const float* __restrict__ bn3_b,
                            const float* __restrict__ w3,    const float* __restrict__ b3,
                            const float* __restrict__ cbias,
                            float* __restrict__ attn_out, float* __restrict__ aggb_out) {
    __shared__ float P[B_][CIN], A[B_][CIN], A2[B_][CIN];
    __shared__ float L[B_][KK_], ATT[B_][KK_];
    const int t = threadIdx.x;          // 256 threads: b*32 + c
    const int b = t >> 5, c = t & 31;

    float pv = p[b*CIN + c];
    P[b][c] = pv;
    A[b][c] = gelu_erf(pv * bn1_g[c] + bn1_b[c]);
    __syncthreads();

    float s = b1[c];
    for (int j = 0; j < CIN; ++j) s += A[b][j] * w1[c*CIN + j];
    A2[b][c] = gelu_erf(s * bn2_g[c] + bn2_b[c]);
    __syncthreads();

    float s2 = b2[c];
    for (int j = 0; j < CIN; ++j) s2 += A2[b][j] * w2[c*CIN + j];
    s2 += pv;                              // residual
    s2 = s2 * bn3_g[c] + bn3_b[c];
    __syncthreads();                        // A no longer read; safe to reuse
    A[b][c] = s2;
    __syncthreads();

    if (c < KK_) {
        float lv = b3[c];
        for (int j = 0; j < CIN; ++j) lv += A[b][j] * w3[c*CIN + j];
        L[b][c] = lv;
    }
    __syncthreads();

    const float T = temperature[0];
    if (c < KK_) {
        float m = fmaxf(fmaxf(L[b][0], L[b][1]), fmaxf(L[b][2], L[b][3]));
        float e = expf((L[b][c] - m) / T);
        float den = 0.f;
        for (int j = 0; j < KK_; ++j) den += expf((L[b][j] - m) / T);
        float av = e / den;
        ATT[b][c] = av;
        attn_out[b*KK_ + c] = av;
    }
    __syncthreads();

    for (int o = c; o < COUT; o += CIN) {
        float sb = 0.f;
        for (int k = 0; k < KK_; ++k) sb += ATT[b][k] * cbias[k*COUT + o];
        aggb_out[b*COUT + o] = sb;
    }
}

// ---------------- 3) aggregate weights to [b][ci][kpos][o] ----------------
__global__ void aggw_kernel(const float* __restrict__ weight,   // [K][O][CI][27]
                            const float* __restrict__ attn,     // [B][K]
                            float* __restrict__ aggw) {         // [B][CI][27][O]
    const int idx = blockIdx.x * 256 + threadIdx.x;   // over [b][ci][kpos][o]
    const int o    = idx & 63;
    int r          = idx >> 6;
    const int kpos = r % 27;  r /= 27;
    const int ci   = r & 31;
    const int b    = r >> 5;
    float s = 0.f;
    #pragma unroll
    for (int k = 0; k < KK_; ++k)
        s += attn[b*KK_ + k] * weight[((k*COUT + o)*CIN + ci)*27 + kpos];
    aggw[idx] = s;
}

// ---------------- 4) direct conv3d ----------------
// block: 256 threads = 4 h-rows x 64 w. Each thread: 32 output channels.
// grid: (H/4, D, B*2)  -- z = b*2 + o_half
__global__ __launch_bounds__(256) void conv_kernel(const float* __restrict__ x,
                                                   const float* __restrict__ aggw, // [B][CI][27][O]
                                                   const float* __restrict__ aggb, // [B][O]
                                                   float* __restrict__ out) {
    const int t  = threadIdx.x;
    const int w  = t & 63;
    const int h  = (blockIdx.x << 2) + (t >> 6);
    const int d  = blockIdx.y;
    const int b  = blockIdx.z >> 1;
    const int oh = blockIdx.z & 1;        // o in [oh*32, oh*32+32)

    float acc[32];
    #pragma unroll
    for (int i = 0; i < 32; ++i) acc[i] = 0.f;

    const float* xb = x + (size_t)b * CIN * DHW;
    const float* wb = aggw + (size_t)b * CIN * 27 * COUT + oh * 32;

    for (int ci = 0; ci < CIN; ++ci) {
        const float* xc = xb + (size_t)ci * DHW;
        const float* wc = wb + ci * 27 * COUT;
        #pragma unroll
        for (int kd = 0; kd < 3; ++kd) {
            const int zd = d + kd - 1;
            const bool vz = (unsigned)zd < DD;
            #pragma unroll
            for (int kh = 0; kh < 3; ++kh) {
                const int yh = h + kh - 1;
                const bool vzy = vz && ((unsigned)yh < HH);
                const float* xr = xc + zd*HW + yh*WW;
                const float* wk = wc + (kd*9 + kh*3)*COUT;
                #pragma unroll
                for (int kw = 0; kw < 3; ++kw) {
                    const int xw = w + kw - 1;
                    const bool v = vzy && ((unsigned)xw < WW);
                    const float xv = v ? xr[xw] : 0.f;
                    const float* wv = wk + kw*COUT;
                    #pragma unroll
                    for (int o = 0; o < 32; ++o)
                        acc[o] = fmaf(xv, wv[o], acc[o]);
                }
            }
        }
    }

    const size_t obase = ((size_t)b*COUT + oh*32) * DHW + (size_t)d*HW + (size_t)h*WW + w;
    #pragma unroll
    for (int o = 0; o < 32; ++o)
        out[obase + (size_t)o*DHW] = acc[o] + aggb[b*COUT + oh*32 + o];
}

// ---------------- launch ----------------
extern "C" void kernel_launch(void* const* d_in, const int* in_sizes, int n_in,
                              void* d_out, int out_size, void* d_ws, size_t ws_size,
                              hipStream_t stream) {
    const float* x           = (const float*)d_in[0];
    const float* weight      = (const float*)d_in[1];
    const float* cbias       = (const float*)d_in[2];
    const float* temperature = (const float*)d_in[3];
    const float* bn1_g       = (const float*)d_in[4];
    const float* bn1_b       = (const float*)d_in[5];
    const float* w1          = (const float*)d_in[6];
    const float* b1          = (const float*)d_in[7];
    const float* bn2_g       = (const float*)d_in[8];
    const float* bn2_b       = (const float*)d_in[9];
    const float* w2          = (const float*)d_in[10];
    const float* b2          = (const float*)d_in[11];
    const float* bn3_g       = (const float*)d_in[12];
    const float* bn3_b       = (const float*)d_in[13];
    const float* w3          = (const float*)d_in[14];
    const float* b3          = (const float*)d_in[15];
    float* out = (float*)d_out;

    float* ws   = (float*)d_ws;
    float* p    = ws;            // 256
    float* attn = ws + 256;      // 32
    float* aggb = ws + 288;      // 512
    float* aggw = ws + 1024;     // 8*32*27*64 = 442368

    pool_kernel<<<B_*CIN, 256, 0, stream>>>(x, p);
    attn_kernel<<<1, 256, 0, stream>>>(p, temperature,
                                       bn1_g, bn1_b, w1, b1,
                                       bn2_g, bn2_b, w2, b2,
                                       bn3_g, bn3_b, w3, b3,
                                       cbias, attn, aggb);
    aggw_kernel<<<(B_*CIN*27*COUT)/256, 256, 0, stream>>>(weight, attn, aggw);
    conv_kernel<<<dim3(HH/4, DD, B_*2), 256, 0, stream>>>(x, aggw, aggb, out);
}

// Round 2
// 343.995 us; speedup vs baseline: 13.6015x; 13.6015x over previous
//
#include <hip/hip_runtime.h>
#include <hip/hip_bf16.h>
#include <math.h>

#define B_   8
#define CIN  32
#define COUT 64
#define KK_  4
#define DD   32
#define HH   64
#define WW   64
#define HW   (HH*WW)        // 4096
#define DHW  (DD*HH*WW)     // 131072

typedef __attribute__((ext_vector_type(8))) short bf16x8;
typedef __attribute__((ext_vector_type(4))) float f32x4;

__device__ __forceinline__ unsigned short f2bf(float f) {
    union { float f; unsigned int u; } v; v.f = f;
    unsigned int r = (v.u + 0x7FFFu + ((v.u >> 16) & 1u)) >> 16;   // RNE
    return (unsigned short)r;
}

// ---------------- 1) global average pool: p[b][c] ----------------
__global__ void pool_kernel(const float* __restrict__ x, float* __restrict__ p) {
    const int row = blockIdx.x;  // b*CIN + c
    const float4* xr = (const float4*)(x + (size_t)row * DHW);
    float s = 0.f;
    for (int i = threadIdx.x; i < DHW/4; i += 256) {
        float4 v = xr[i];
        s += (v.x + v.y) + (v.z + v.w);
    }
    __shared__ float red[256];
    red[threadIdx.x] = s;
    __syncthreads();
    for (int off = 128; off > 0; off >>= 1) {
        if (threadIdx.x < off) red[threadIdx.x] += red[threadIdx.x + off];
        __syncthreads();
    }
    if (threadIdx.x == 0) p[row] = red[0] * (1.f / (float)DHW);
}

// ---------------- 2) attention MLP + softmax + agg bias ----------------
__device__ __forceinline__ float gelu_erf(float v) {
    return 0.5f * v * (1.f + erff(v * 0.70710678118654752f));
}

__global__ void attn_kernel(const float* __restrict__ p,
                            const float* __restrict__ temperature,
                            const float* __restrict__ bn1_g, const float* __restrict__ bn1_b,
                            const float* __restrict__ w1,    const float* __restrict__ b1,
                            const float* __restrict__ bn2_g, const float* __restrict__ bn2_b,
                            const float* __restrict__ w2,    const float* __restrict__ b2,
                            const float* __restrict__ bn3_g, const float* __restrict__ bn3_b,
                            const float* __restrict__ w3,    const float* __restrict__ b3,
                            const float* __restrict__ cbias,
                            float* __restrict__ attn_out, float* __restrict__ aggb_out) {
    __shared__ float A[B_][CIN], A2[B_][CIN];
    __shared__ float L[B_][KK_], ATT[B_][KK_];
    const int t = threadIdx.x;          // 256 threads: b*32 + c
    const int b = t >> 5, c = t & 31;

    float pv = p[b*CIN + c];
    A[b][c] = gelu_erf(pv * bn1_g[c] + bn1_b[c]);
    __syncthreads();

    float s = b1[c];
    for (int j = 0; j < CIN; ++j) s += A[b][j] * w1[c*CIN + j];
    A2[b][c] = gelu_erf(s * bn2_g[c] + bn2_b[c]);
    __syncthreads();

    float s2 = b2[c];
    for (int j = 0; j < CIN; ++j) s2 += A2[b][j] * w2[c*CIN + j];
    s2 += pv;                              // residual
    s2 = s2 * bn3_g[c] + bn3_b[c];
    __syncthreads();
    A[b][c] = s2;
    __syncthreads();

    if (c < KK_) {
        float lv = b3[c];
        for (int j = 0; j < CIN; ++j) lv += A[b][j] * w3[c*CIN + j];
        L[b][c] = lv;
    }
    __syncthreads();

    const float T = temperature[0];
    if (c < KK_) {
        float m = fmaxf(fmaxf(L[b][0], L[b][1]), fmaxf(L[b][2], L[b][3]));
        float e = expf((L[b][c] - m) / T);
        float den = 0.f;
        for (int j = 0; j < KK_; ++j) den += expf((L[b][j] - m) / T);
        float av = e / den;
        ATT[b][c] = av;
        attn_out[b*KK_ + c] = av;
    }
    __syncthreads();

    for (int o = c; o < COUT; o += CIN) {
        float sb = 0.f;
        for (int k = 0; k < KK_; ++k) sb += ATT[b][k] * cbias[k*COUT + o];
        aggb_out[b*COUT + o] = sb;
    }
}

// ---------------- 3) aggregate weights -> bf16 wt[b][kpos][co][ci] ----------------
__global__ void aggw_kernel(const float* __restrict__ weight,   // [K][O][CI][27]
                            const float* __restrict__ attn,     // [B][K]
                            unsigned short* __restrict__ wt) {  // [B][27][O][CI] bf16
    const int idx = blockIdx.x * 256 + threadIdx.x;   // B*27*64*32 = 442368
    const int ci   = idx & 31;
    const int co   = (idx >> 5) & 63;
    int r          = idx >> 11;
    const int kpos = r % 27;
    const int b    = r / 27;
    float s = 0.f;
    #pragma unroll
    for (int k = 0; k < KK_; ++k)
        s += attn[b*KK_ + k] * weight[((k*COUT + co)*CIN + ci)*27 + kpos];
    wt[idx] = f2bf(s);
}

// ---------------- 4) transpose x -> bf16 xt[b][d][h][w][ci] ----------------
// grid (H/4, D, B), 256 threads: thread = (r=t>>6 -> h row, w=t&63)
__global__ __launch_bounds__(256) void transpose_kernel(const float* __restrict__ x,
                                                        unsigned short* __restrict__ xt) {
    const int t = threadIdx.x;
    const int r = t >> 6, w = t & 63;
    const int h = (blockIdx.x << 2) + r;
    const int d = blockIdx.y;
    const int b = blockIdx.z;

    const float* xb = x + (size_t)b * CIN * DHW + (size_t)d * HW + (size_t)h * WW + w;
    unsigned int packed[CIN/2];
    #pragma unroll
    for (int c2 = 0; c2 < CIN/2; ++c2) {
        unsigned int lo = f2bf(xb[(size_t)(2*c2  ) * DHW]);
        unsigned int hi = f2bf(xb[(size_t)(2*c2+1) * DHW]);
        packed[c2] = lo | (hi << 16);
    }
    uint4* dst = (uint4*)(xt + ((size_t)((b*DD + d)*HH + h)*WW + w) * CIN);
    #pragma unroll
    for (int q = 0; q < 4; ++q)
        dst[q] = make_uint4(packed[4*q], packed[4*q+1], packed[4*q+2], packed[4*q+3]);
}

// ---------------- 5) MFMA conv ----------------
// block 256 = 4 waves; wave = one (b,d,h) row: M=64 co x N=64 w, K-loop 27 offsets x 32 ci
// grid (H/4, D, B)
__global__ __launch_bounds__(256) void conv_mfma(const unsigned short* __restrict__ xt,
                                                 const unsigned short* __restrict__ wt,
                                                 const float* __restrict__ aggb,
                                                 float* __restrict__ out) {
    const int t    = threadIdx.x;
    const int lane = t & 63;
    const int wv   = t >> 6;
    const int col  = lane & 15;      // w-within-frag / co-within-frag
    const int kq   = lane >> 4;      // k quarter: ci base = kq*8
    const int h    = (blockIdx.x << 2) + wv;
    const int d    = blockIdx.y;
    const int b    = blockIdx.z;

    f32x4 acc[4][4];                 // [af(co)][fs(w)]
    #pragma unroll
    for (int i = 0; i < 4; ++i)
        #pragma unroll
        for (int j = 0; j < 4; ++j)
            acc[i][j] = (f32x4){0.f, 0.f, 0.f, 0.f};

    const unsigned short* wtb = wt + (size_t)b * 27 * COUT * CIN;
    const unsigned short* xtb = xt + (size_t)b * DHW * CIN;
    const bf16x8 bz = {};

    for (int kd = 0; kd < 3; ++kd) {
        const int zd = d + kd - 1;
        if ((unsigned)zd >= DD) continue;
        for (int kh = 0; kh < 3; ++kh) {
            const int yh = h + kh - 1;
            if ((unsigned)yh >= HH) continue;
            const unsigned short* xrow = xtb + (size_t)(zd*HH + yh) * WW * CIN + kq*8;
            const unsigned short* wrow = wtb + (size_t)((kd*3 + kh)*3) * COUT * CIN + col*CIN + kq*8;
            #pragma unroll
            for (int kw = 0; kw < 3; ++kw) {
                const unsigned short* wk = wrow + kw*COUT*CIN;
                bf16x8 a0 = *(const bf16x8*)(wk);
                bf16x8 a1 = *(const bf16x8*)(wk + 16*CIN);
                bf16x8 a2 = *(const bf16x8*)(wk + 32*CIN);
                bf16x8 a3 = *(const bf16x8*)(wk + 48*CIN);
                #pragma unroll
                for (int fs = 0; fs < 4; ++fs) {
                    const int w = fs*16 + col + kw - 1;
                    bf16x8 bv = *(const bf16x8*)(xrow + w*CIN);  // in-bounds of ws even at w=-1/64
                    if ((unsigned)w >= WW) bv = bz;
                    acc[0][fs] = __builtin_amdgcn_mfma_f32_16x16x32_bf16(a0, bv, acc[0][fs], 0, 0, 0);
                    acc[1][fs] = __builtin_amdgcn_mfma_f32_16x16x32_bf16(a1, bv, acc[1][fs], 0, 0, 0);
                    acc[2][fs] = __builtin_amdgcn_mfma_f32_16x16x32_bf16(a2, bv, acc[2][fs], 0, 0, 0);
                    acc[3][fs] = __builtin_amdgcn_mfma_f32_16x16x32_bf16(a3, bv, acc[3][fs], 0, 0, 0);
                }
            }
        }
    }

    // epilogue: co = af*16 + kq*4 + j ; w = fs*16 + col
    const size_t sp = (size_t)(d*HH + h) * WW;
    #pragma unroll
    for (int af = 0; af < 4; ++af) {
        #pragma unroll
        for (int j = 0; j < 4; ++j) {
            const int co = af*16 + kq*4 + j;
            const float bb = aggb[b*COUT + co];
            float* orow = out + ((size_t)(b*COUT + co)) * DHW + sp;
            #pragma unroll
            for (int fs = 0; fs < 4; ++fs)
                orow[fs*16 + col] = acc[af][fs][j] + bb;
        }
    }
}

// ---------------- launch ----------------
extern "C" void kernel_launch(void* const* d_in, const int* in_sizes, int n_in,
                              void* d_out, int out_size, void* d_ws, size_t ws_size,
                              hipStream_t stream) {
    const float* x           = (const float*)d_in[0];
    const float* weight      = (const float*)d_in[1];
    const float* cbias       = (const float*)d_in[2];
    const float* temperature = (const float*)d_in[3];
    const float* bn1_g       = (const float*)d_in[4];
    const float* bn1_b       = (const float*)d_in[5];
    const float* w1          = (const float*)d_in[6];
    const float* b1          = (const float*)d_in[7];
    const float* bn2_g       = (const float*)d_in[8];
    const float* bn2_b       = (const float*)d_in[9];
    const float* w2          = (const float*)d_in[10];
    const float* b2          = (const float*)d_in[11];
    const float* bn3_g       = (const float*)d_in[12];
    const float* bn3_b       = (const float*)d_in[13];
    const float* w3          = (const float*)d_in[14];
    const float* b3          = (const float*)d_in[15];
    float* out = (float*)d_out;

    char* ws = (char*)d_ws;
    float*          p    = (float*)(ws);                  // 256 f
    float*          attn = (float*)(ws + 1024);           // 32 f
    float*          aggb = (float*)(ws + 2048);           // 512 f
    unsigned short* wt   = (unsigned short*)(ws + 8192);  // 442368 bf16 (884736 B)
    unsigned short* xt   = (unsigned short*)(ws + (1u<<20)); // 33554432 bf16 (64 MiB)

    transpose_kernel<<<dim3(HH/4, DD, B_), 256, 0, stream>>>(x, xt);
    pool_kernel<<<B_*CIN, 256, 0, stream>>>(x, p);
    attn_kernel<<<1, 256, 0, stream>>>(p, temperature,
                                       bn1_g, bn1_b, w1, b1,
                                       bn2_g, bn2_b, w2, b2,
                                       bn3_g, bn3_b, w3, b3,
                                       cbias, attn, aggb);
    aggw_kernel<<<(B_*27*COUT*CIN)/256, 256, 0, stream>>>(weight, attn, wt);
    conv_mfma<<<dim3(HH/4, DD, B_), 256, 0, stream>>>(xt, wt, aggb, out);
}

// Round 3
// 215.678 us; speedup vs baseline: 21.6937x; 1.5949x over previous
//
#include <hip/hip_runtime.h>
#include <hip/hip_bf16.h>
#include <math.h>

#define B_   8
#define CIN  32
#define COUT 64
#define KK_  4
#define DD   32
#define HH   64
#define WW   64
#define HW   (HH*WW)        // 4096
#define DHW  (DD*HH*WW)     // 131072

typedef __attribute__((ext_vector_type(8)))  short bf16x8;
typedef __attribute__((ext_vector_type(16))) float f32x16;

__device__ __forceinline__ unsigned short f2bf(float f) {
    union { float f; unsigned int u; } v; v.f = f;
    return (unsigned short)((v.u + 0x7FFFu + ((v.u >> 16) & 1u)) >> 16);   // RNE
}
__device__ __forceinline__ float bf2f(unsigned short s) {
    union { unsigned int u; float f; } v; v.u = ((unsigned int)s) << 16;
    return v.f;
}
__device__ __forceinline__ void gll16(const void* g, void* l) {
    __builtin_amdgcn_global_load_lds(
        (const __attribute__((address_space(1))) void*)g,
        (__attribute__((address_space(3))) void*)l, 16, 0, 0);
}

// ---------------- 1) transpose x -> bf16 xt rows: [b][d][h] x [oct4][w64 swz][8ci]
// swizzle: 16B chunk for w stored at byte (w*16)^(oct<<4) within its 1024B oct section.
__global__ __launch_bounds__(256) void transpose_kernel(const float* __restrict__ x,
                                                        unsigned short* __restrict__ xt) {
    const int t = threadIdx.x;
    const int r = t >> 6, w = t & 63;
    const int h = (blockIdx.x << 2) + r;
    const int d = blockIdx.y, b = blockIdx.z;

    const float* xb = x + (size_t)b*CIN*DHW + (size_t)d*HW + (size_t)h*WW + w;
    unsigned int packed[CIN/2];
    #pragma unroll
    for (int c2 = 0; c2 < CIN/2; ++c2) {
        unsigned int lo = f2bf(xb[(size_t)(2*c2)   * DHW]);
        unsigned int hi = f2bf(xb[(size_t)(2*c2+1) * DHW]);
        packed[c2] = lo | (hi << 16);
    }
    char* row = (char*)xt + (size_t)((b*DD + d)*HH + h) * 4096;
    #pragma unroll
    for (int q = 0; q < 4; ++q) {
        uint4 v = make_uint4(packed[4*q], packed[4*q+1], packed[4*q+2], packed[4*q+3]);
        *(uint4*)(row + q*1024 + (((w << 4)) ^ (q << 4))) = v;
    }
}

// ---------------- 2) pooling partials from xt: pblk[b][d][ci] ----------------
__global__ __launch_bounds__(256) void pool2_kernel(const unsigned short* __restrict__ xt,
                                                    float* __restrict__ pblk) {
    const int t = threadIdx.x;
    const int oct = t >> 6, wi = t & 63;       // each wave owns one ci-oct
    const int d = blockIdx.x, b = blockIdx.y;
    const char* base = (const char*)xt + (size_t)((b*DD + d)*HH) * 4096 + oct*1024 + wi*16;
    float acc[8];
    #pragma unroll
    for (int j = 0; j < 8; ++j) acc[j] = 0.f;
    for (int h = 0; h < HH; ++h) {
        bf16x8 v = *(const bf16x8*)(base + (size_t)h * 4096);
        #pragma unroll
        for (int j = 0; j < 8; ++j) acc[j] += bf2f((unsigned short)v[j]);
    }
    #pragma unroll
    for (int off = 32; off > 0; off >>= 1) {
        #pragma unroll
        for (int j = 0; j < 8; ++j) acc[j] += __shfl_xor(acc[j], off);
    }
    if ((t & 63) == 0) {
        #pragma unroll
        for (int j = 0; j < 8; ++j)
            pblk[(b*DD + d)*CIN + oct*8 + j] = acc[j];
    }
}

// ---------------- 3) attention MLP + softmax + agg bias (includes pblk reduce) ----
__device__ __forceinline__ float gelu_erf(float v) {
    return 0.5f * v * (1.f + erff(v * 0.70710678118654752f));
}

__global__ void attn_kernel(const float* __restrict__ pblk,
                            const float* __restrict__ temperature,
                            const float* __restrict__ bn1_g, const float* __restrict__ bn1_b,
                            const float* __restrict__ w1,    const float* __restrict__ b1,
                            const float* __restrict__ bn2_g, const float* __restrict__ bn2_b,
                            const float* __restrict__ w2,    const float* __restrict__ b2,
                            const float* __restrict__ bn3_g, const float* __restrict__ bn3_b,
                            const float* __restrict__ w3,    const float* __restrict__ b3,
                            const float* __restrict__ cbias,
                            float* __restrict__ attn_out, float* __restrict__ aggb_out) {
    __shared__ float A[B_][CIN], A2[B_][CIN];
    __shared__ float L[B_][KK_], ATT[B_][KK_];
    const int t = threadIdx.x;          // 256 threads: b*32 + c
    const int b = t >> 5, c = t & 31;

    float pv = 0.f;
    for (int dd = 0; dd < DD; ++dd) pv += pblk[(b*DD + dd)*CIN + c];
    pv *= (1.f / (float)DHW);

    A[b][c] = gelu_erf(pv * bn1_g[c] + bn1_b[c]);
    __syncthreads();

    float s = b1[c];
    for (int j = 0; j < CIN; ++j) s += A[b][j] * w1[c*CIN + j];
    A2[b][c] = gelu_erf(s * bn2_g[c] + bn2_b[c]);
    __syncthreads();

    float s2 = b2[c];
    for (int j = 0; j < CIN; ++j) s2 += A2[b][j] * w2[c*CIN + j];
    s2 += pv;                              // residual
    s2 = s2 * bn3_g[c] + bn3_b[c];
    __syncthreads();
    A[b][c] = s2;
    __syncthreads();

    if (c < KK_) {
        float lv = b3[c];
        for (int j = 0; j < CIN; ++j) lv += A[b][j] * w3[c*CIN + j];
        L[b][c] = lv;
    }
    __syncthreads();

    const float T = temperature[0];
    if (c < KK_) {
        float m = fmaxf(fmaxf(L[b][0], L[b][1]), fmaxf(L[b][2], L[b][3]));
        float e = expf((L[b][c] - m) / T);
        float den = 0.f;
        for (int j = 0; j < KK_; ++j) den += expf((L[b][j] - m) / T);
        float av = e / den;
        ATT[b][c] = av;
        attn_out[b*KK_ + c] = av;
    }
    __syncthreads();

    for (int o = c; o < COUT; o += CIN) {
        float sb = 0.f;
        for (int k = 0; k < KK_; ++k) sb += ATT[b][k] * cbias[k*COUT + o];
        aggb_out[b*COUT + o] = sb;
    }
}

// ---------------- 4) aggregate weights -> bf16 wt[b][kpos][co][ci] ----------------
__global__ void aggw_kernel(const float* __restrict__ weight,   // [K][O][CI][27]
                            const float* __restrict__ attn,     // [B][K]
                            unsigned short* __restrict__ wt) {  // [B][27][O][CI] bf16
    const int idx = blockIdx.x * 256 + threadIdx.x;   // B*27*64*32 = 442368
    const int ci   = idx & 31;
    const int co   = (idx >> 5) & 63;
    int r          = idx >> 11;
    const int kpos = r % 27;
    const int b    = r / 27;
    float s = 0.f;
    #pragma unroll
    for (int k = 0; k < KK_; ++k)
        s += attn[b*KK_ + k] * weight[((k*COUT + co)*CIN + ci)*27 + kpos];
    wt[idx] = f2bf(s);
}

// ---------------- 5) MFMA conv, LDS-staged ----------------
// block 256 = 4 waves (2d x 2h rows), each wave M=64co x N=64w, 32x32x16 MFMA
// grid (H/2, D/2, B); LDS: 16 rows (4 zd x 4 yh) x 4096 B = 64 KiB
__global__ __launch_bounds__(256) void conv_mfma(const unsigned short* __restrict__ xt,
                                                 const unsigned short* __restrict__ wt,
                                                 const float* __restrict__ aggb,
                                                 float* __restrict__ out) {
    __shared__ char smem[16*4096];
    const int t = threadIdx.x;
    const int lane = t & 63, wv = t >> 6;
    const int lw = lane & 31, lh = lane >> 5;
    const int dv = wv >> 1, hv = wv & 1;
    const int h0 = blockIdx.x << 1, d0 = blockIdx.y << 1;
    const int b = blockIdx.z;

    // zero-fill out-of-range rows (block-uniform branches)
    {
        const uint4 z4 = make_uint4(0u, 0u, 0u, 0u);
        #pragma unroll
        for (int rr = 0; rr < 16; ++rr) {
            const int zd = d0 - 1 + (rr >> 2), yh = h0 - 1 + (rr & 3);
            if ((unsigned)zd >= DD || (unsigned)yh >= HH)
                *(uint4*)&smem[rr*4096 + t*16] = z4;
        }
    }
    // stage in-bounds rows: wave wv copies oct section wv of each row (1 KiB/instr)
    {
        const char* xb = (const char*)xt;
        for (int rr = 0; rr < 16; ++rr) {
            const int zd = d0 - 1 + (rr >> 2), yh = h0 - 1 + (rr & 3);
            if ((unsigned)zd < DD && (unsigned)yh < HH) {
                const char* src = xb + (size_t)((b*DD + zd)*HH + yh)*4096 + wv*1024 + lane*16;
                gll16(src, &smem[rr*4096 + wv*1024]);
            }
        }
    }
    __syncthreads();

    const f32x16 fz = {};
    f32x16 acc[2][2];
    #pragma unroll
    for (int cb = 0; cb < 2; ++cb)
        #pragma unroll
        for (int fs = 0; fs < 2; ++fs)
            acc[cb][fs] = fz;

    const char* wtb = (const char*)wt + (size_t)b * 27 * 4096;
    const int a_off = lw*64 + lh*16;      // co=cb*32+lw (64B/row), ci=kh2*16+lh*8 (2B/ci)
    const int o0 = lh, o1 = 2 + lh;       // ci-octs for k-half 0 / 1
    const bf16x8 bz = {};

    for (int kd = 0; kd < 3; ++kd) {
        for (int kh = 0; kh < 3; ++kh) {
            const int rb = (((dv + kd) << 2) + (hv + kh)) << 12;   // LDS row base
            const char* wk0 = wtb + (size_t)((kd*3 + kh)*3) * 4096;
            #pragma unroll
            for (int kw = 0; kw < 3; ++kw) {
                const char* wk = wk0 + kw*4096;
                const bf16x8 a00 = *(const bf16x8*)(wk + a_off);          // cb=0, kh2=0
                const bf16x8 a01 = *(const bf16x8*)(wk + 32 + a_off);     // cb=0, kh2=1
                const bf16x8 a10 = *(const bf16x8*)(wk + 2048 + a_off);   // cb=1, kh2=0
                const bf16x8 a11 = *(const bf16x8*)(wk + 2048 + 32 + a_off);
                #pragma unroll
                for (int fs = 0; fs < 2; ++fs) {
                    const int wp = (fs << 5) + lw + kw - 1;
                    const bool oob = ((unsigned)wp >= (unsigned)WW);
                    const int wpc = oob ? ((wp < 0) ? 0 : (WW - 1)) : wp;
                    bf16x8 b0 = *(const bf16x8*)&smem[rb + o0*1024 + ((wpc << 4) ^ (o0 << 4))];
                    bf16x8 b1 = *(const bf16x8*)&smem[rb + o1*1024 + ((wpc << 4) ^ (o1 << 4))];
                    if (oob) { b0 = bz; b1 = bz; }
                    acc[0][fs] = __builtin_amdgcn_mfma_f32_32x32x16_bf16(a00, b0, acc[0][fs], 0, 0, 0);
                    acc[0][fs] = __builtin_amdgcn_mfma_f32_32x32x16_bf16(a01, b1, acc[0][fs], 0, 0, 0);
                    acc[1][fs] = __builtin_amdgcn_mfma_f32_32x32x16_bf16(a10, b0, acc[1][fs], 0, 0, 0);
                    acc[1][fs] = __builtin_amdgcn_mfma_f32_32x32x16_bf16(a11, b1, acc[1][fs], 0, 0, 0);
                }
            }
        }
    }

    // epilogue: co = cb*32 + (reg&3) + 8*(reg>>2) + 4*lh ; w = fs*32 + lw
    const int d = d0 + dv, h = h0 + hv;
    float* ob = out + (size_t)b*COUT*DHW + (size_t)(d*HH + h)*WW;
    const float* ab = aggb + b*COUT;
    #pragma unroll
    for (int cb = 0; cb < 2; ++cb) {
        #pragma unroll
        for (int reg = 0; reg < 16; ++reg) {
            const int co = (cb << 5) + (reg & 3) + ((reg >> 2) << 3) + (lh << 2);
            const float bb = ab[co];
            ob[(size_t)co*DHW + lw]      = acc[cb][0][reg] + bb;
            ob[(size_t)co*DHW + 32 + lw] = acc[cb][1][reg] + bb;
        }
    }
}

// ---------------- launch ----------------
extern "C" void kernel_launch(void* const* d_in, const int* in_sizes, int n_in,
                              void* d_out, int out_size, void* d_ws, size_t ws_size,
                              hipStream_t stream) {
    const float* x           = (const float*)d_in[0];
    const float* weight      = (const float*)d_in[1];
    const float* cbias       = (const float*)d_in[2];
    const float* temperature = (const float*)d_in[3];
    const float* bn1_g       = (const float*)d_in[4];
    const float* bn1_b       = (const float*)d_in[5];
    const float* w1          = (const float*)d_in[6];
    const float* b1          = (const float*)d_in[7];
    const float* bn2_g       = (const float*)d_in[8];
    const float* bn2_b       = (const float*)d_in[9];
    const float* w2          = (const float*)d_in[10];
    const float* b2          = (const float*)d_in[11];
    const float* bn3_g       = (const float*)d_in[12];
    const float* bn3_b       = (const float*)d_in[13];
    const float* w3          = (const float*)d_in[14];
    const float* b3          = (const float*)d_in[15];
    float* out = (float*)d_out;

    char* ws = (char*)d_ws;
    float*          attn = (float*)(ws + 1024);           // 32 f
    float*          aggb = (float*)(ws + 2048);           // 512 f
    float*          pblk = (float*)(ws + 16384);          // 8*32*32 f = 32 KiB
    unsigned short* wt   = (unsigned short*)(ws + 65536); // 884736 B
    unsigned short* xt   = (unsigned short*)(ws + (1u << 20)); // 64 MiB

    transpose_kernel<<<dim3(HH/4, DD, B_), 256, 0, stream>>>(x, xt);
    pool2_kernel<<<dim3(DD, B_), 256, 0, stream>>>(xt, pblk);
    attn_kernel<<<1, 256, 0, stream>>>(pblk, temperature,
                                       bn1_g, bn1_b, w1, b1,
                                       bn2_g, bn2_b, w2, b2,
                                       bn3_g, bn3_b, w3, b3,
                                       cbias, attn, aggb);
    aggw_kernel<<<(B_*27*COUT*CIN)/256, 256, 0, stream>>>(weight, attn, wt);
    conv_mfma<<<dim3(HH/2, DD/2, B_), 256, 0, stream>>>(xt, wt, aggb, out);
}